// Round 1
// baseline (212.620 us; speedup 1.0000x reference)
//
#include <hip/hip_runtime.h>

// ---------------- problem constants ----------------
#define HW        262144   // 512*512
#define NB        4
#define NID       15
#define K_BUCKETS 1024

// ---------------- workspace layout (in floats) ----------------
// [0,240)   stats[b][i][4]  : cnt, sum_x, sum_y, sum_sigma
// [240,244) seedbg[b]
// [244,424) accum[b][i][3]  : var_sum, seed_sum, distm_sum
// [424,484) lovasz[b*15+i]
// [512,...) hist (as uint)  : [60][K][2] (fg,bg)
#define WS_STATS  0
#define WS_SEEDBG 240
#define WS_ACCUM  244
#define WS_LOV    424
#define WS_HIST   512
#define WS_TOTAL_FLOATS (WS_HIST + 60 * K_BUCKETS * 2)

__device__ __forceinline__ float fast_tanh(float x) {
    // 1 - 2/(e^{2x}+1): inf-safe (e=inf -> 1, e=0 -> -1)
    return 1.0f - 2.0f / (__expf(2.0f * x) + 1.0f);
}
__device__ __forceinline__ float fast_sigmoid(float x) {
    return 1.0f / (1.0f + __expf(-x));
}

// ---------------- kernel A: per-(b,id) mask stats + seed_bg ----------------
__global__ __launch_bounds__(256) void statsKernel(const float* __restrict__ pred,
                                                   const int* __restrict__ inst,
                                                   const int* __restrict__ lab,
                                                   float* __restrict__ ws) {
    const int b   = blockIdx.y;
    const int tid = threadIdx.x;
    const int base = blockIdx.x * 4096;           // 64 blocks/image * 4096 px
    const float inv511 = 1.0f / 511.0f;

    float cnt[NID], sx[NID], sy[NID], ss[NID];
#pragma unroll
    for (int i = 0; i < NID; ++i) { cnt[i] = 0.f; sx[i] = 0.f; sy[i] = 0.f; ss[i] = 0.f; }
    float sbg = 0.f;

    const int ib = b * HW;
    const float* sig = pred + (((size_t)(b * 4 + 2)) << 18);
    const float* p3  = pred + (((size_t)(b * 4 + 3)) << 18);

    for (int it = 0; it < 16; ++it) {
        int p = base + it * 256 + tid;
        int iid = inst[ib + p];
        int lb  = lab[ib + p];
        float sg = sig[p];
        float seed = fast_sigmoid(p3[p]);
        if (lb == 0) sbg += seed * seed;
        float xs = (float)(p & 511) * inv511;
        float ys = (float)(p >> 9) * inv511;
#pragma unroll
        for (int i = 0; i < NID; ++i) {
            if (iid == i + 1) { cnt[i] += 1.f; sx[i] += xs; sy[i] += ys; ss[i] += sg; }
        }
    }

    const int ln = tid & 63;
#pragma unroll
    for (int i = 0; i < NID; ++i) {
        float v0 = cnt[i], v1 = sx[i], v2 = sy[i], v3 = ss[i];
#pragma unroll
        for (int m = 32; m; m >>= 1) {
            v0 += __shfl_xor(v0, m, 64);
            v1 += __shfl_xor(v1, m, 64);
            v2 += __shfl_xor(v2, m, 64);
            v3 += __shfl_xor(v3, m, 64);
        }
        if (ln == 0) {
            float* st = ws + WS_STATS + (b * NID + i) * 4;
            atomicAdd(st + 0, v0);
            atomicAdd(st + 1, v1);
            atomicAdd(st + 2, v2);
            atomicAdd(st + 3, v3);
        }
    }
#pragma unroll
    for (int m = 32; m; m >>= 1) sbg += __shfl_xor(sbg, m, 64);
    if (ln == 0) atomicAdd(ws + WS_SEEDBG + b, sbg);
}

// ---------------- kernel C: dist map, histogram, masked sums ----------------
__global__ __launch_bounds__(256) void mainKernel(const float* __restrict__ pred,
                                                  const int* __restrict__ inst,
                                                  float* __restrict__ ws) {
    __shared__ unsigned s_hist[K_BUCKETS * 2];
    __shared__ float s_red[4][3];

    const int b  = blockIdx.z;
    const int i  = blockIdx.y;      // id-1
    const int id = i + 1;

    const float* st = ws + WS_STATS + (b * NID + i) * 4;
    float cnt = st[0];
    if (cnt == 0.f) return;         // uniform exit; hist stays zero, masked later
    float cnt_s = fmaxf(cnt, 1.f);
    float cx = st[1] / cnt_s, cy = st[2] / cnt_s, sigm = st[3] / cnt_s;
    float s = __expf(10.f * sigm);

    const int tid = threadIdx.x;
    for (int j = tid; j < K_BUCKETS * 2; j += 256) s_hist[j] = 0u;
    __syncthreads();

    const int ib = b * HW;
    const float* p0 = pred + (((size_t)(b * 4 + 0)) << 18);
    const float* p1 = pred + (((size_t)(b * 4 + 1)) << 18);
    const float* p2 = pred + (((size_t)(b * 4 + 2)) << 18);
    const float* p3 = pred + (((size_t)(b * 4 + 3)) << 18);
    const int base = blockIdx.x * (HW / 16);    // 16384 px/block
    const float inv511 = 1.0f / 511.0f;

    float vs = 0.f, ssum = 0.f, ds = 0.f;
    for (int it = 0; it < 64; ++it) {
        int p = base + it * 256 + tid;
        int iid = inst[ib + p];
        float th0 = fast_tanh(p0[p]);
        float th1 = fast_tanh(p1[p]);
        float xs = (float)(p & 511) * inv511;
        float ys = (float)(p >> 9) * inv511;
        float dx = th0 + xs - cx;
        float dy = th1 + ys - cy;
        float d2 = dx * dx + dy * dy;
        float dist = __expf(-d2 * s);
        bool m = (iid == id);
        float err = m ? (2.f - 2.f * dist) : (2.f * dist);
        int bk = (int)(err * (K_BUCKETS * 0.5f));
        bk = min(bk, K_BUCKETS - 1);
        atomicAdd(&s_hist[bk * 2 + (m ? 0 : 1)], 1u);
        if (m) {
            float dsg = p2[p] - sigm;
            vs += dsg * dsg;
            float e2 = fast_sigmoid(p3[p]) - dist;
            ssum += e2 * e2;
            ds += dist;
        }
    }

    // block-reduce the three masked sums
#pragma unroll
    for (int m = 32; m; m >>= 1) {
        vs   += __shfl_xor(vs, m, 64);
        ssum += __shfl_xor(ssum, m, 64);
        ds   += __shfl_xor(ds, m, 64);
    }
    int wv = tid >> 6, ln = tid & 63;
    if (ln == 0) { s_red[wv][0] = vs; s_red[wv][1] = ssum; s_red[wv][2] = ds; }
    __syncthreads();
    if (tid == 0) {
        float a = 0.f, c = 0.f, d = 0.f;
        for (int w = 0; w < 4; ++w) { a += s_red[w][0]; c += s_red[w][1]; d += s_red[w][2]; }
        float* ac = ws + WS_ACCUM + (b * NID + i) * 3;
        atomicAdd(ac + 0, a);
        atomicAdd(ac + 1, c);
        atomicAdd(ac + 2, d);
    }

    // flush LDS histogram (the syncthreads above also fences the hist atomics)
    unsigned* gh = (unsigned*)(ws + WS_HIST) + (size_t)(b * NID + i) * (K_BUCKETS * 2);
    for (int j = tid; j < K_BUCKETS * 2; j += 256) {
        unsigned v = s_hist[j];
        if (v) atomicAdd(&gh[j], v);
    }
}

// ---------------- kernel D: Lovász hinge via bucket scan ----------------
__global__ __launch_bounds__(64) void lovaszKernel(float* __restrict__ ws) {
    const int t    = blockIdx.x;    // 0..59 = b*15+i
    const int lane = threadIdx.x;   // 0..63
    const unsigned* hist = (const unsigned*)(ws + WS_HIST) + (size_t)t * (K_BUCKETS * 2);
    float G = ws[WS_STATS + t * 4];
    float sum = 0.f;
    if (G > 0.f) {
        const int SEG = K_BUCKETS / 64;   // 16 buckets per lane (descending-error order)
        float fgs[SEG], bgs[SEG];
        float Fl = 0.f, Bl = 0.f;
#pragma unroll
        for (int q = 0; q < SEG; ++q) {
            int k = K_BUCKETS - 1 - (lane * SEG + q);
            fgs[q] = (float)hist[k * 2];
            bgs[q] = (float)hist[k * 2 + 1];
            Fl += fgs[q]; Bl += bgs[q];
        }
        // inclusive scan across lanes, then make exclusive
        float Fe = Fl, Be = Bl;
#pragma unroll
        for (int d = 1; d < 64; d <<= 1) {
            float fu = __shfl_up(Fe, d, 64);
            float bu = __shfl_up(Be, d, 64);
            if (lane >= d) { Fe += fu; Be += bu; }
        }
        Fe -= Fl; Be -= Bl;
        float F = Fe, B = Be;
        float Jprev = 1.f - (G - F) / (G + B);   // (0,0) -> 0 since G>0
        const float ew = 2.f / K_BUCKETS;
#pragma unroll
        for (int q = 0; q < SEG; ++q) {
            int k = K_BUCKETS - 1 - (lane * SEG + q);
            F += fgs[q]; B += bgs[q];
            float J = 1.f - (G - F) / (G + B);
            sum += ((float)k + 0.5f) * ew * (J - Jprev);
            Jprev = J;
        }
#pragma unroll
        for (int m = 32; m; m >>= 1) sum += __shfl_xor(sum, m, 64);
    }
    if (lane == 0) ws[WS_LOV + t] = sum;
}

// ---------------- kernel E: compose final scalar ----------------
__global__ void finalKernel(const float* __restrict__ ws, float* __restrict__ out) {
    if (threadIdx.x != 0 || blockIdx.x != 0) return;
    float total = 0.f;
    for (int b = 0; b < NB; ++b) {
        float obj = 0.f, instl = 0.f, varl = 0.f, intral = 0.f, seedl = 0.f;
        for (int i = 0; i < NID; ++i) {
            const float* st = ws + WS_STATS + (b * NID + i) * 4;
            float cnt = st[0];
            if (cnt > 0.f) {
                float cnt_s = fmaxf(cnt, 1.f);
                obj += 1.f;
                const float* ac = ws + WS_ACCUM + (b * NID + i) * 3;
                varl  += ac[0] / cnt_s;
                seedl += ac[1];
                intral += 1.f - ac[2] / cnt_s;
                instl += ws[WS_LOV + b * NID + i];
            }
        }
        float obj_s = fmaxf(obj, 1.f);
        float loss = instl / obj_s
                   + 10.f * (varl / obj_s)
                   + (ws[WS_SEEDBG + b] + seedl) / (float)HW
                   + 5.f * intral;
        total += loss;
    }
    out[0] = total * 0.25f;
}

extern "C" void kernel_launch(void* const* d_in, const int* in_sizes, int n_in,
                              void* d_out, int out_size, void* d_ws, size_t ws_size,
                              hipStream_t stream) {
    const float* pred = (const float*)d_in[0];
    const int*   inst = (const int*)d_in[1];
    const int*   lab  = (const int*)d_in[2];
    float* ws  = (float*)d_ws;
    float* out = (float*)d_out;

    hipMemsetAsync(d_ws, 0, WS_TOTAL_FLOATS * sizeof(float), stream);
    statsKernel<<<dim3(64, NB), 256, 0, stream>>>(pred, inst, lab, ws);
    mainKernel<<<dim3(16, NID, NB), 256, 0, stream>>>(pred, inst, ws);
    lovaszKernel<<<60, 64, 0, stream>>>(ws);
    finalKernel<<<1, 64, 0, stream>>>(ws, out);
}

// Round 2
// 109.478 us; speedup vs baseline: 1.9421x; 1.9421x over previous
//
#include <hip/hip_runtime.h>

// ---------------- problem constants ----------------
#define HW        262144   // 512*512
#define NB        4
#define NID       15
#define K_BUCKETS 1024

// ---------------- workspace layout (in floats) ----------------
// [0,240)   stats[b][i][4]  : cnt, sum_x, sum_y, sum_sigma
// [240,244) seedbg[b]
// [244,424) accum[b][i][3]  : var_sum, seed_sum, distm_sum
// [424,484) lovasz[b*15+i]
// [512,...) hist (as uint)  : [60][K][2] (fg,bg)
#define WS_STATS  0
#define WS_SEEDBG 240
#define WS_ACCUM  244
#define WS_LOV    424
#define WS_HIST   512
#define WS_TOTAL_FLOATS (WS_HIST + 60 * K_BUCKETS * 2)

__device__ __forceinline__ float fast_tanh(float x) {
    // 1 - 2/(e^{2x}+1): inf-safe (e=inf -> 1, e=0 -> -1)
    return 1.0f - 2.0f / (__expf(2.0f * x) + 1.0f);
}
__device__ __forceinline__ float fast_sigmoid(float x) {
    return 1.0f / (1.0f + __expf(-x));
}

// ---------------- kernel A: per-(b,id) mask stats + seed_bg ----------------
// 512 blocks (128/image), 256 threads, 8 px/thread via int4/float4 loads.
// Per-pixel accumulation goes straight into a 61-float LDS array via
// atomicAdd (ds_add_f32): each pixel belongs to exactly one id, so this
// replaces 61 per-thread register accumulators + 366 shuffles.
__global__ __launch_bounds__(256) void statsKernel(const float* __restrict__ pred,
                                                   const int* __restrict__ inst,
                                                   const int* __restrict__ lab,
                                                   float* __restrict__ ws) {
    __shared__ float s_acc[61];   // [i*4+c] for 15 ids, [60]=seed_bg
    const int b   = blockIdx.y;
    const int tid = threadIdx.x;
    if (tid < 61) s_acc[tid] = 0.f;
    __syncthreads();

    const int ib = b * HW;
    const float* sig = pred + (((size_t)(b * 4 + 2)) << 18);
    const float* p3  = pred + (((size_t)(b * 4 + 3)) << 18);
    const float inv511 = 1.0f / 511.0f;
    const int base = blockIdx.x * 2048;       // 128 blocks/image * 2048 px

    float sbg = 0.f;
#pragma unroll
    for (int u = 0; u < 2; ++u) {
        const int p = base + u * 1024 + tid * 4;
        const int4   i4 = *(const int4*)(inst + ib + p);
        const int4   l4 = *(const int4*)(lab + ib + p);
        const float4 g4 = *(const float4*)(sig + p);
        const float4 t4 = *(const float4*)(p3 + p);
        const int   x0 = p & 511;
        const float ys = (float)(p >> 9) * inv511;

        {
            float sd = fast_sigmoid(t4.x);
            sbg += (l4.x == 0) ? sd * sd : 0.f;
            if (i4.x > 0) {
                int o = (i4.x - 1) * 4;
                atomicAdd(&s_acc[o + 0], 1.f);
                atomicAdd(&s_acc[o + 1], (float)(x0 + 0) * inv511);
                atomicAdd(&s_acc[o + 2], ys);
                atomicAdd(&s_acc[o + 3], g4.x);
            }
        }
        {
            float sd = fast_sigmoid(t4.y);
            sbg += (l4.y == 0) ? sd * sd : 0.f;
            if (i4.y > 0) {
                int o = (i4.y - 1) * 4;
                atomicAdd(&s_acc[o + 0], 1.f);
                atomicAdd(&s_acc[o + 1], (float)(x0 + 1) * inv511);
                atomicAdd(&s_acc[o + 2], ys);
                atomicAdd(&s_acc[o + 3], g4.y);
            }
        }
        {
            float sd = fast_sigmoid(t4.z);
            sbg += (l4.z == 0) ? sd * sd : 0.f;
            if (i4.z > 0) {
                int o = (i4.z - 1) * 4;
                atomicAdd(&s_acc[o + 0], 1.f);
                atomicAdd(&s_acc[o + 1], (float)(x0 + 2) * inv511);
                atomicAdd(&s_acc[o + 2], ys);
                atomicAdd(&s_acc[o + 3], g4.z);
            }
        }
        {
            float sd = fast_sigmoid(t4.w);
            sbg += (l4.w == 0) ? sd * sd : 0.f;
            if (i4.w > 0) {
                int o = (i4.w - 1) * 4;
                atomicAdd(&s_acc[o + 0], 1.f);
                atomicAdd(&s_acc[o + 1], (float)(x0 + 3) * inv511);
                atomicAdd(&s_acc[o + 2], ys);
                atomicAdd(&s_acc[o + 3], g4.w);
            }
        }
    }

    // reduce seed_bg within each wave, then into LDS
#pragma unroll
    for (int m = 32; m; m >>= 1) sbg += __shfl_xor(sbg, m, 64);
    if ((tid & 63) == 0) atomicAdd(&s_acc[60], sbg);
    __syncthreads();

    // flush block partials (layout matches ws: (b*15+i)*4+c == b*60 + tid)
    if (tid < 60) atomicAdd(ws + WS_STATS + b * 60 + tid, s_acc[tid]);
    if (tid == 60) atomicAdd(ws + WS_SEEDBG + b, s_acc[60]);
}

// ---------------- kernel C: dist map, histogram, masked sums ----------------
__global__ __launch_bounds__(256) void mainKernel(const float* __restrict__ pred,
                                                  const int* __restrict__ inst,
                                                  float* __restrict__ ws) {
    __shared__ unsigned s_hist[K_BUCKETS * 2];
    __shared__ float s_red[4][3];

    const int b  = blockIdx.z;
    const int i  = blockIdx.y;      // id-1
    const int id = i + 1;

    const float* st = ws + WS_STATS + (b * NID + i) * 4;
    float cnt = st[0];
    if (cnt == 0.f) return;         // uniform exit; hist stays zero, masked later
    float cnt_s = fmaxf(cnt, 1.f);
    float cx = st[1] / cnt_s, cy = st[2] / cnt_s, sigm = st[3] / cnt_s;
    float s = __expf(10.f * sigm);

    const int tid = threadIdx.x;
    for (int j = tid; j < K_BUCKETS * 2; j += 256) s_hist[j] = 0u;
    __syncthreads();

    const int ib = b * HW;
    const float* p0 = pred + (((size_t)(b * 4 + 0)) << 18);
    const float* p1 = pred + (((size_t)(b * 4 + 1)) << 18);
    const float* p2 = pred + (((size_t)(b * 4 + 2)) << 18);
    const float* p3 = pred + (((size_t)(b * 4 + 3)) << 18);
    const int base = blockIdx.x * (HW / 16);    // 16384 px/block
    const float inv511 = 1.0f / 511.0f;

    float vs = 0.f, ssum = 0.f, ds = 0.f;
    for (int it = 0; it < 64; ++it) {
        int p = base + it * 256 + tid;
        int iid = inst[ib + p];
        float th0 = fast_tanh(p0[p]);
        float th1 = fast_tanh(p1[p]);
        float xs = (float)(p & 511) * inv511;
        float ys = (float)(p >> 9) * inv511;
        float dx = th0 + xs - cx;
        float dy = th1 + ys - cy;
        float d2 = dx * dx + dy * dy;
        float dist = __expf(-d2 * s);
        bool m = (iid == id);
        float err = m ? (2.f - 2.f * dist) : (2.f * dist);
        int bk = (int)(err * (K_BUCKETS * 0.5f));
        bk = min(bk, K_BUCKETS - 1);
        atomicAdd(&s_hist[bk * 2 + (m ? 0 : 1)], 1u);
        if (m) {
            float dsg = p2[p] - sigm;
            vs += dsg * dsg;
            float e2 = fast_sigmoid(p3[p]) - dist;
            ssum += e2 * e2;
            ds += dist;
        }
    }

    // block-reduce the three masked sums
#pragma unroll
    for (int m = 32; m; m >>= 1) {
        vs   += __shfl_xor(vs, m, 64);
        ssum += __shfl_xor(ssum, m, 64);
        ds   += __shfl_xor(ds, m, 64);
    }
    int wv = tid >> 6, ln = tid & 63;
    if (ln == 0) { s_red[wv][0] = vs; s_red[wv][1] = ssum; s_red[wv][2] = ds; }
    __syncthreads();
    if (tid == 0) {
        float a = 0.f, c = 0.f, d = 0.f;
        for (int w = 0; w < 4; ++w) { a += s_red[w][0]; c += s_red[w][1]; d += s_red[w][2]; }
        float* ac = ws + WS_ACCUM + (b * NID + i) * 3;
        atomicAdd(ac + 0, a);
        atomicAdd(ac + 1, c);
        atomicAdd(ac + 2, d);
    }

    // flush LDS histogram (the syncthreads above also fences the hist atomics)
    unsigned* gh = (unsigned*)(ws + WS_HIST) + (size_t)(b * NID + i) * (K_BUCKETS * 2);
    for (int j = tid; j < K_BUCKETS * 2; j += 256) {
        unsigned v = s_hist[j];
        if (v) atomicAdd(&gh[j], v);
    }
}

// ---------------- kernel D: Lovász hinge via bucket scan ----------------
__global__ __launch_bounds__(64) void lovaszKernel(float* __restrict__ ws) {
    const int t    = blockIdx.x;    // 0..59 = b*15+i
    const int lane = threadIdx.x;   // 0..63
    const unsigned* hist = (const unsigned*)(ws + WS_HIST) + (size_t)t * (K_BUCKETS * 2);
    float G = ws[WS_STATS + t * 4];
    float sum = 0.f;
    if (G > 0.f) {
        const int SEG = K_BUCKETS / 64;   // 16 buckets per lane (descending-error order)
        float fgs[SEG], bgs[SEG];
        float Fl = 0.f, Bl = 0.f;
#pragma unroll
        for (int q = 0; q < SEG; ++q) {
            int k = K_BUCKETS - 1 - (lane * SEG + q);
            fgs[q] = (float)hist[k * 2];
            bgs[q] = (float)hist[k * 2 + 1];
            Fl += fgs[q]; Bl += bgs[q];
        }
        // inclusive scan across lanes, then make exclusive
        float Fe = Fl, Be = Bl;
#pragma unroll
        for (int d = 1; d < 64; d <<= 1) {
            float fu = __shfl_up(Fe, d, 64);
            float bu = __shfl_up(Be, d, 64);
            if (lane >= d) { Fe += fu; Be += bu; }
        }
        Fe -= Fl; Be -= Bl;
        float F = Fe, B = Be;
        float Jprev = 1.f - (G - F) / (G + B);   // (0,0) -> 0 since G>0
        const float ew = 2.f / K_BUCKETS;
#pragma unroll
        for (int q = 0; q < SEG; ++q) {
            int k = K_BUCKETS - 1 - (lane * SEG + q);
            F += fgs[q]; B += bgs[q];
            float J = 1.f - (G - F) / (G + B);
            sum += ((float)k + 0.5f) * ew * (J - Jprev);
            Jprev = J;
        }
#pragma unroll
        for (int m = 32; m; m >>= 1) sum += __shfl_xor(sum, m, 64);
    }
    if (lane == 0) ws[WS_LOV + t] = sum;
}

// ---------------- kernel E: compose final scalar ----------------
__global__ void finalKernel(const float* __restrict__ ws, float* __restrict__ out) {
    if (threadIdx.x != 0 || blockIdx.x != 0) return;
    float total = 0.f;
    for (int b = 0; b < NB; ++b) {
        float obj = 0.f, instl = 0.f, varl = 0.f, intral = 0.f, seedl = 0.f;
        for (int i = 0; i < NID; ++i) {
            const float* st = ws + WS_STATS + (b * NID + i) * 4;
            float cnt = st[0];
            if (cnt > 0.f) {
                float cnt_s = fmaxf(cnt, 1.f);
                obj += 1.f;
                const float* ac = ws + WS_ACCUM + (b * NID + i) * 3;
                varl  += ac[0] / cnt_s;
                seedl += ac[1];
                intral += 1.f - ac[2] / cnt_s;
                instl += ws[WS_LOV + b * NID + i];
            }
        }
        float obj_s = fmaxf(obj, 1.f);
        float loss = instl / obj_s
                   + 10.f * (varl / obj_s)
                   + (ws[WS_SEEDBG + b] + seedl) / (float)HW
                   + 5.f * intral;
        total += loss;
    }
    out[0] = total * 0.25f;
}

extern "C" void kernel_launch(void* const* d_in, const int* in_sizes, int n_in,
                              void* d_out, int out_size, void* d_ws, size_t ws_size,
                              hipStream_t stream) {
    const float* pred = (const float*)d_in[0];
    const int*   inst = (const int*)d_in[1];
    const int*   lab  = (const int*)d_in[2];
    float* ws  = (float*)d_ws;
    float* out = (float*)d_out;

    hipMemsetAsync(d_ws, 0, WS_TOTAL_FLOATS * sizeof(float), stream);
    statsKernel<<<dim3(128, NB), 256, 0, stream>>>(pred, inst, lab, ws);
    mainKernel<<<dim3(16, NID, NB), 256, 0, stream>>>(pred, inst, ws);
    lovaszKernel<<<60, 64, 0, stream>>>(ws);
    finalKernel<<<1, 64, 0, stream>>>(ws, out);
}

// Round 3
// 95.063 us; speedup vs baseline: 2.2366x; 1.1516x over previous
//
#include <hip/hip_runtime.h>

// ---------------- problem constants ----------------
#define HW        262144   // 512*512
#define NB        4
#define NID       15
#define K_BUCKETS 1024

// ---------------- workspace layout (in floats) ----------------
#define WS_STATS  0                       // [60][4]: cnt, sum_x, sum_y, sum_sigma
#define WS_SEEDBG 240                     // [4]
#define WS_ACCUM  244                     // [60][3]: var_sum, seed_sum, distm_sum
#define WS_LOV    424                     // [60]
#define WS_HIST   512                     // uints [60][K][2] (fg,bg)
#define WS_HIST_UINTS (60 * K_BUCKETS * 2)
#define WS_MAPS   (WS_HIST + WS_HIST_UINTS)   // 123392
#define MAP_SZ    (NB * HW)                   // 1048576 floats per map
#define WS_EMBX   (WS_MAPS)
#define WS_EMBY   (WS_MAPS + MAP_SZ)
#define WS_SEED   (WS_MAPS + 2 * MAP_SZ)
#define WS_TOTAL_FLOATS (WS_MAPS + 3 * MAP_SZ)   // ~12.5 MB

__device__ __forceinline__ float rcp_fast(float x) {
    return __builtin_amdgcn_rcpf(x);      // v_rcp_f32, 1 instr (vs ~10-instr exact div)
}
__device__ __forceinline__ float fast_tanh(float x) {
    // 1 - 2/(e^{2x}+1): inf-safe (exp=inf -> 1, exp=0 -> -1)
    return 1.0f - 2.0f * rcp_fast(__expf(2.0f * x) + 1.0f);
}
__device__ __forceinline__ float fast_sigmoid(float x) {
    return rcp_fast(1.0f + __expf(-x));
}

// ---------------- kernel 1: fused stats + map precompute ----------------
// Reads all 4 pred channels + inst + lab once; computes tanh/sigmoid ONCE
// per pixel (vs 15x in mainKernel) and writes embx/emby/seed maps.
// Stats go through a 61-float LDS atomic array.
template<bool MAPS>
__global__ __launch_bounds__(256) void prepKernel(const float* __restrict__ pred,
                                                  const int* __restrict__ inst,
                                                  const int* __restrict__ lab,
                                                  float* __restrict__ ws) {
    __shared__ float s_acc[61];   // [i*4+c] for 15 ids, [60]=seed_bg
    const int b   = blockIdx.y;
    const int tid = threadIdx.x;
    if (tid < 61) s_acc[tid] = 0.f;
    __syncthreads();

    const int ib = b * HW;
    const float* p0 = pred + (((size_t)(b * 4 + 0)) << 18);
    const float* p1 = pred + (((size_t)(b * 4 + 1)) << 18);
    const float* p2 = pred + (((size_t)(b * 4 + 2)) << 18);
    const float* p3 = pred + (((size_t)(b * 4 + 3)) << 18);
    float* embx = ws + WS_EMBX + ib;
    float* emby = ws + WS_EMBY + ib;
    float* seedm = ws + WS_SEED + ib;
    const float inv511 = 1.0f / 511.0f;
    const int base = blockIdx.x * 2048;       // 128 blocks/image

    float sbg = 0.f;
#pragma unroll
    for (int u = 0; u < 2; ++u) {
        const int p = base + u * 1024 + tid * 4;
        const int4   i4 = *(const int4*)(inst + ib + p);
        const int4   l4 = *(const int4*)(lab + ib + p);
        const float4 a4 = *(const float4*)(p0 + p);
        const float4 b4 = *(const float4*)(p1 + p);
        const float4 g4 = *(const float4*)(p2 + p);
        const float4 t4 = *(const float4*)(p3 + p);
        const float xs0 = (float)(p & 511) * inv511;
        const float ys  = (float)(p >> 9) * inv511;

        float4 ex, ey, sd;
        ex.x = fast_tanh(a4.x) + xs0;
        ex.y = fast_tanh(a4.y) + xs0 + inv511;
        ex.z = fast_tanh(a4.z) + xs0 + 2.f * inv511;
        ex.w = fast_tanh(a4.w) + xs0 + 3.f * inv511;
        ey.x = fast_tanh(b4.x) + ys;
        ey.y = fast_tanh(b4.y) + ys;
        ey.z = fast_tanh(b4.z) + ys;
        ey.w = fast_tanh(b4.w) + ys;
        sd.x = fast_sigmoid(t4.x);
        sd.y = fast_sigmoid(t4.y);
        sd.z = fast_sigmoid(t4.z);
        sd.w = fast_sigmoid(t4.w);
        if (MAPS) {
            *(float4*)(embx + p) = ex;
            *(float4*)(emby + p) = ey;
            *(float4*)(seedm + p) = sd;
        }

        sbg += (l4.x == 0) ? sd.x * sd.x : 0.f;
        sbg += (l4.y == 0) ? sd.y * sd.y : 0.f;
        sbg += (l4.z == 0) ? sd.z * sd.z : 0.f;
        sbg += (l4.w == 0) ? sd.w * sd.w : 0.f;

        if (i4.x > 0) {
            int o = (i4.x - 1) * 4;
            atomicAdd(&s_acc[o + 0], 1.f);
            atomicAdd(&s_acc[o + 1], xs0);
            atomicAdd(&s_acc[o + 2], ys);
            atomicAdd(&s_acc[o + 3], g4.x);
        }
        if (i4.y > 0) {
            int o = (i4.y - 1) * 4;
            atomicAdd(&s_acc[o + 0], 1.f);
            atomicAdd(&s_acc[o + 1], xs0 + inv511);
            atomicAdd(&s_acc[o + 2], ys);
            atomicAdd(&s_acc[o + 3], g4.y);
        }
        if (i4.z > 0) {
            int o = (i4.z - 1) * 4;
            atomicAdd(&s_acc[o + 0], 1.f);
            atomicAdd(&s_acc[o + 1], xs0 + 2.f * inv511);
            atomicAdd(&s_acc[o + 2], ys);
            atomicAdd(&s_acc[o + 3], g4.z);
        }
        if (i4.w > 0) {
            int o = (i4.w - 1) * 4;
            atomicAdd(&s_acc[o + 0], 1.f);
            atomicAdd(&s_acc[o + 1], xs0 + 3.f * inv511);
            atomicAdd(&s_acc[o + 2], ys);
            atomicAdd(&s_acc[o + 3], g4.w);
        }
    }

#pragma unroll
    for (int m = 32; m; m >>= 1) sbg += __shfl_xor(sbg, m, 64);
    if ((tid & 63) == 0) atomicAdd(&s_acc[60], sbg);
    __syncthreads();

    if (tid < 60) atomicAdd(ws + WS_STATS + b * 60 + tid, s_acc[tid]);
    if (tid == 60) atomicAdd(ws + WS_SEEDBG + b, s_acc[60]);
}

// ---------------- kernel 2: dist map, histogram, masked sums ----------------
// One (b,id) per blockIdx.{z,y}; 32 x-splits -> 1920 blocks (~7.5/CU).
// With MAPS: reads precomputed embx/emby/seed -> 1 exp + ~12 VALU per pixel.
template<bool MAPS>
__global__ __launch_bounds__(256) void mainKernel(const float* __restrict__ pred,
                                                  const int* __restrict__ inst,
                                                  float* __restrict__ ws) {
    __shared__ unsigned s_hist[K_BUCKETS * 2];
    __shared__ float s_red[4][3];

    const int b  = blockIdx.z;
    const int i  = blockIdx.y;      // id-1
    const int id = i + 1;

    const float* st = ws + WS_STATS + (b * NID + i) * 4;
    float cnt = st[0];
    if (cnt == 0.f) return;         // uniform exit; hist stays zero, masked later
    float cnt_s = fmaxf(cnt, 1.f);
    float inv_cnt = rcp_fast(cnt_s);
    float cx = st[1] * inv_cnt, cy = st[2] * inv_cnt, sigm = st[3] * inv_cnt;
    float s = __expf(10.f * sigm);

    const int tid = threadIdx.x;
    for (int j = tid; j < K_BUCKETS * 2; j += 256) s_hist[j] = 0u;
    __syncthreads();

    const int ib = b * HW;
    const float* p0 = pred + (((size_t)(b * 4 + 0)) << 18);
    const float* p1 = pred + (((size_t)(b * 4 + 1)) << 18);
    const float* p2 = pred + (((size_t)(b * 4 + 2)) << 18);
    const float* p3 = pred + (((size_t)(b * 4 + 3)) << 18);
    const float* embx = ws + WS_EMBX + ib;
    const float* emby = ws + WS_EMBY + ib;
    const float* seedm = ws + WS_SEED + ib;
    const int base = blockIdx.x * (HW / 32);    // 8192 px/block
    const float inv511 = 1.0f / 511.0f;

    float vs = 0.f, ssum = 0.f, ds = 0.f;
    for (int it = 0; it < 8; ++it) {
        const int p = base + it * 1024 + tid * 4;
        const int4 i4 = *(const int4*)(inst + ib + p);
        const float4 g4 = *(const float4*)(p2 + p);
        float4 ex, ey, sd;
        if (MAPS) {
            ex = *(const float4*)(embx + p);
            ey = *(const float4*)(emby + p);
            sd = *(const float4*)(seedm + p);
        } else {
            const float4 a4 = *(const float4*)(p0 + p);
            const float4 b4 = *(const float4*)(p1 + p);
            const float4 t4 = *(const float4*)(p3 + p);
            const float xs0 = (float)(p & 511) * inv511;
            const float ys  = (float)(p >> 9) * inv511;
            ex.x = fast_tanh(a4.x) + xs0;
            ex.y = fast_tanh(a4.y) + xs0 + inv511;
            ex.z = fast_tanh(a4.z) + xs0 + 2.f * inv511;
            ex.w = fast_tanh(a4.w) + xs0 + 3.f * inv511;
            ey.x = fast_tanh(b4.x) + ys;
            ey.y = fast_tanh(b4.y) + ys;
            ey.z = fast_tanh(b4.z) + ys;
            ey.w = fast_tanh(b4.w) + ys;
            sd.x = fast_sigmoid(t4.x);
            sd.y = fast_sigmoid(t4.y);
            sd.z = fast_sigmoid(t4.z);
            sd.w = fast_sigmoid(t4.w);
        }

#define PIXEL(C)                                                         \
        {                                                                \
            float dx = ex.C - cx, dy = ey.C - cy;                        \
            float dist = __expf(-(dx * dx + dy * dy) * s);               \
            bool m = (i4.C == id);                                       \
            float err = m ? (2.f - 2.f * dist) : (2.f * dist);           \
            int bk = min((int)(err * (K_BUCKETS * 0.5f)), K_BUCKETS - 1);\
            atomicAdd(&s_hist[bk * 2 + (m ? 0 : 1)], 1u);                \
            if (m) {                                                     \
                float dsg = g4.C - sigm;                                 \
                vs += dsg * dsg;                                         \
                float e2 = sd.C - dist;                                  \
                ssum += e2 * e2;                                         \
                ds += dist;                                              \
            }                                                            \
        }
        PIXEL(x) PIXEL(y) PIXEL(z) PIXEL(w)
#undef PIXEL
    }

    // block-reduce the three masked sums
#pragma unroll
    for (int m = 32; m; m >>= 1) {
        vs   += __shfl_xor(vs, m, 64);
        ssum += __shfl_xor(ssum, m, 64);
        ds   += __shfl_xor(ds, m, 64);
    }
    int wv = tid >> 6, ln = tid & 63;
    if (ln == 0) { s_red[wv][0] = vs; s_red[wv][1] = ssum; s_red[wv][2] = ds; }
    __syncthreads();
    if (tid == 0) {
        float a = 0.f, c = 0.f, d = 0.f;
        for (int w = 0; w < 4; ++w) { a += s_red[w][0]; c += s_red[w][1]; d += s_red[w][2]; }
        float* ac = ws + WS_ACCUM + (b * NID + i) * 3;
        atomicAdd(ac + 0, a);
        atomicAdd(ac + 1, c);
        atomicAdd(ac + 2, d);
    }

    // flush LDS histogram (the syncthreads above also fences the hist atomics)
    unsigned* gh = (unsigned*)(ws + WS_HIST) + (size_t)(b * NID + i) * (K_BUCKETS * 2);
    for (int j = tid; j < K_BUCKETS * 2; j += 256) {
        unsigned v = s_hist[j];
        if (v) atomicAdd(&gh[j], v);
    }
}

// ---------------- kernel 3: Lovász hinge via bucket scan ----------------
__global__ __launch_bounds__(64) void lovaszKernel(float* __restrict__ ws) {
    const int t    = blockIdx.x;    // 0..59 = b*15+i
    const int lane = threadIdx.x;   // 0..63
    const unsigned* hist = (const unsigned*)(ws + WS_HIST) + (size_t)t * (K_BUCKETS * 2);
    float G = ws[WS_STATS + t * 4];
    float sum = 0.f;
    if (G > 0.f) {
        const int SEG = K_BUCKETS / 64;   // 16 buckets per lane (descending-error order)
        float fgs[SEG], bgs[SEG];
        float Fl = 0.f, Bl = 0.f;
#pragma unroll
        for (int q = 0; q < SEG; ++q) {
            int k = K_BUCKETS - 1 - (lane * SEG + q);
            fgs[q] = (float)hist[k * 2];
            bgs[q] = (float)hist[k * 2 + 1];
            Fl += fgs[q]; Bl += bgs[q];
        }
        // inclusive scan across lanes, then make exclusive
        float Fe = Fl, Be = Bl;
#pragma unroll
        for (int d = 1; d < 64; d <<= 1) {
            float fu = __shfl_up(Fe, d, 64);
            float bu = __shfl_up(Be, d, 64);
            if (lane >= d) { Fe += fu; Be += bu; }
        }
        Fe -= Fl; Be -= Bl;
        float F = Fe, B = Be;
        float Jprev = 1.f - (G - F) / (G + B);   // (0,0) -> 0 since G>0
        const float ew = 2.f / K_BUCKETS;
#pragma unroll
        for (int q = 0; q < SEG; ++q) {
            int k = K_BUCKETS - 1 - (lane * SEG + q);
            F += fgs[q]; B += bgs[q];
            float J = 1.f - (G - F) / (G + B);
            sum += ((float)k + 0.5f) * ew * (J - Jprev);
            Jprev = J;
        }
#pragma unroll
        for (int m = 32; m; m >>= 1) sum += __shfl_xor(sum, m, 64);
    }
    if (lane == 0) ws[WS_LOV + t] = sum;
}

// ---------------- kernel 4: compose final scalar ----------------
__global__ void finalKernel(const float* __restrict__ ws, float* __restrict__ out) {
    if (threadIdx.x != 0 || blockIdx.x != 0) return;
    float total = 0.f;
    for (int b = 0; b < NB; ++b) {
        float obj = 0.f, instl = 0.f, varl = 0.f, intral = 0.f, seedl = 0.f;
        for (int i = 0; i < NID; ++i) {
            const float* st = ws + WS_STATS + (b * NID + i) * 4;
            float cnt = st[0];
            if (cnt > 0.f) {
                float cnt_s = fmaxf(cnt, 1.f);
                obj += 1.f;
                const float* ac = ws + WS_ACCUM + (b * NID + i) * 3;
                varl  += ac[0] / cnt_s;
                seedl += ac[1];
                intral += 1.f - ac[2] / cnt_s;
                instl += ws[WS_LOV + b * NID + i];
            }
        }
        float obj_s = fmaxf(obj, 1.f);
        float loss = instl / obj_s
                   + 10.f * (varl / obj_s)
                   + (ws[WS_SEEDBG + b] + seedl) / (float)HW
                   + 5.f * intral;
        total += loss;
    }
    out[0] = total * 0.25f;
}

extern "C" void kernel_launch(void* const* d_in, const int* in_sizes, int n_in,
                              void* d_out, int out_size, void* d_ws, size_t ws_size,
                              hipStream_t stream) {
    const float* pred = (const float*)d_in[0];
    const int*   inst = (const int*)d_in[1];
    const int*   lab  = (const int*)d_in[2];
    float* ws  = (float*)d_ws;
    float* out = (float*)d_out;

    const bool maps = ws_size >= (size_t)WS_TOTAL_FLOATS * sizeof(float);

    // zero stats/accum/hist region only; maps are fully overwritten
    hipMemsetAsync(d_ws, 0, (size_t)WS_MAPS * sizeof(float), stream);
    if (maps) {
        prepKernel<true><<<dim3(128, NB), 256, 0, stream>>>(pred, inst, lab, ws);
        mainKernel<true><<<dim3(32, NID, NB), 256, 0, stream>>>(pred, inst, ws);
    } else {
        prepKernel<false><<<dim3(128, NB), 256, 0, stream>>>(pred, inst, lab, ws);
        mainKernel<false><<<dim3(32, NID, NB), 256, 0, stream>>>(pred, inst, ws);
    }
    lovaszKernel<<<60, 64, 0, stream>>>(ws);
    finalKernel<<<1, 64, 0, stream>>>(ws, out);
}

// Round 4
// 86.605 us; speedup vs baseline: 2.4551x; 1.0977x over previous
//
#include <hip/hip_runtime.h>

// ---------------- problem constants ----------------
#define HW     262144      // 512*512
#define NB     4
#define NID    15
#define KB     256         // lovasz histogram buckets (err approx <= 2/KB * dJ ~ 0.01)
#define CHUNKS 128         // hist chunk-splits per image
#define PXC    (HW / CHUNKS)   // 2048 px per hist block

// ---------------- workspace layout (float offsets) ----------------
#define WS_STATR  0                         // [4 replicas][256] : (b*60 + i*4 + c)
#define WS_SEEDBG 1024                      // [4]
#define WS_ACCR   1028                      // [4 replicas][192] : (b*48 + i*3 + c)
#define WS_LOV    1796                      // [60]
#define WS_CTRL   2048                      // control region (memset)
#define WS_HIST   2048                      // u32 region: [NB][CHUNKS][NID][KB*2]
#define HIST_U32  (NB * CHUNKS * NID * KB * 2)   // 3,932,160
#define WS_EMBX   (WS_HIST + HIST_U32)
#define MAP_SZ    (NB * HW)
#define WS_EMBY   (WS_EMBX + MAP_SZ)
#define WS_SEEDM  (WS_EMBY + MAP_SZ)
#define WS_TOTAL  (WS_SEEDM + MAP_SZ)       // ~28.3 MB (ws is 256 MB per harness poison fill)

__device__ __forceinline__ float rcp_fast(float x) { return __builtin_amdgcn_rcpf(x); }
__device__ __forceinline__ float fast_tanh(float x) {
    return 1.0f - 2.0f * rcp_fast(__expf(2.0f * x) + 1.0f);   // inf-safe
}
__device__ __forceinline__ float fast_sigmoid(float x) {
    return rcp_fast(1.0f + __expf(-x));
}

// ---------------- kernel 1: stats + map precompute ----------------
// 256 blocks/image (1024 total, ~4/CU, 16 waves/CU). 4 px/thread.
// Stats accumulate into 16 per-lane-group LDS copies (collisions ~1.1 vs 4.3),
// flushed into 4 global replica arrays (L2 same-address chains /4).
__global__ __launch_bounds__(256) void prepKernel(const float* __restrict__ pred,
                                                  const int* __restrict__ inst,
                                                  const int* __restrict__ lab,
                                                  float* __restrict__ ws) {
    __shared__ float s_acc[16][68];   // [group][(i*4+c) | 60=seed_bg], stride 68 for bank spread
    const int b   = blockIdx.y;
    const int tid = threadIdx.x;
    for (int j = tid; j < 16 * 68; j += 256) ((float*)s_acc)[j] = 0.f;
    __syncthreads();

    const int grp = tid >> 4;          // 16-lane group id, 0..15
    const int ib = b * HW;
    const float* p0 = pred + (((size_t)(b * 4 + 0)) << 18);
    const float* p1 = pred + (((size_t)(b * 4 + 1)) << 18);
    const float* p2 = pred + (((size_t)(b * 4 + 2)) << 18);
    const float* p3 = pred + (((size_t)(b * 4 + 3)) << 18);
    float* embx  = ws + WS_EMBX + ib;
    float* emby  = ws + WS_EMBY + ib;
    float* seedm = ws + WS_SEEDM + ib;
    const float inv511 = 1.0f / 511.0f;

    const int p = blockIdx.x * 1024 + tid * 4;
    const int4   i4 = *(const int4*)(inst + ib + p);
    const int4   l4 = *(const int4*)(lab + ib + p);
    const float4 a4 = *(const float4*)(p0 + p);
    const float4 b4 = *(const float4*)(p1 + p);
    const float4 g4 = *(const float4*)(p2 + p);
    const float4 t4 = *(const float4*)(p3 + p);
    const float xs0 = (float)(p & 511) * inv511;
    const float ys  = (float)(p >> 9) * inv511;

    float4 ex, ey, sd;
    ex.x = fast_tanh(a4.x) + xs0;
    ex.y = fast_tanh(a4.y) + xs0 + inv511;
    ex.z = fast_tanh(a4.z) + xs0 + 2.f * inv511;
    ex.w = fast_tanh(a4.w) + xs0 + 3.f * inv511;
    ey.x = fast_tanh(b4.x) + ys;
    ey.y = fast_tanh(b4.y) + ys;
    ey.z = fast_tanh(b4.z) + ys;
    ey.w = fast_tanh(b4.w) + ys;
    sd.x = fast_sigmoid(t4.x);
    sd.y = fast_sigmoid(t4.y);
    sd.z = fast_sigmoid(t4.z);
    sd.w = fast_sigmoid(t4.w);
    *(float4*)(embx + p)  = ex;
    *(float4*)(emby + p)  = ey;
    *(float4*)(seedm + p) = sd;

    float sbg = 0.f;
    sbg += (l4.x == 0) ? sd.x * sd.x : 0.f;
    sbg += (l4.y == 0) ? sd.y * sd.y : 0.f;
    sbg += (l4.z == 0) ? sd.z * sd.z : 0.f;
    sbg += (l4.w == 0) ? sd.w * sd.w : 0.f;

#define ACC_PX(IID, XS, SG)                                   \
    if ((IID) > 0) {                                          \
        float* a = &s_acc[grp][((IID) - 1) * 4];              \
        atomicAdd(a + 0, 1.f);                                \
        atomicAdd(a + 1, (XS));                               \
        atomicAdd(a + 2, ys);                                 \
        atomicAdd(a + 3, (SG));                               \
    }
    ACC_PX(i4.x, xs0, g4.x)
    ACC_PX(i4.y, xs0 + inv511, g4.y)
    ACC_PX(i4.z, xs0 + 2.f * inv511, g4.z)
    ACC_PX(i4.w, xs0 + 3.f * inv511, g4.w)
#undef ACC_PX

#pragma unroll
    for (int m = 32; m; m >>= 1) sbg += __shfl_xor(sbg, m, 64);
    if ((tid & 63) == 0) atomicAdd(&s_acc[grp][60], sbg);
    __syncthreads();

    if (tid < 61) {
        float tot = 0.f;
#pragma unroll
        for (int q = 0; q < 16; ++q) tot += s_acc[q][tid];
        if (tid < 60) atomicAdd(ws + WS_STATR + (blockIdx.x & 3) * 256 + b * 60 + tid, tot);
        else          atomicAdd(ws + WS_SEEDBG + b, tot);
    }
}

// ---------------- kernel 2: all-ids histogram + fg sums ----------------
// Grid (CHUNKS, NB) = 512 blocks, 256 threads, 2048 px/block (8 px/thread).
// Per pixel: ONE load of {inst, embx, emby, seed, sigma}, then all 15 ids'
// dist/bucket into 15 per-id LDS hists. Flush = plain coalesced stores (no
// global atomics). fg sums (var/seed/intra) via 16-group LDS copies.
__global__ __launch_bounds__(256) void histKernel(const float* __restrict__ pred,
                                                  const int* __restrict__ inst,
                                                  float* __restrict__ ws) {
    __shared__ unsigned s_hist[NID][KB * 2];   // 30720 B
    __shared__ float4   s_stat4[NID];          // cx, cy, sigm, s
    __shared__ float    s_facc[16][48];        // fg accum copies: [grp][i*3+c]

    const int b     = blockIdx.y;
    const int chunk = blockIdx.x;
    const int tid   = threadIdx.x;

    if (tid < NID) {
        float cnt = 0.f, sx = 0.f, sy = 0.f, ss = 0.f;
#pragma unroll
        for (int r = 0; r < 4; ++r) {
            const float* st = ws + WS_STATR + r * 256 + b * 60 + tid * 4;
            cnt += st[0]; sx += st[1]; sy += st[2]; ss += st[3];
        }
        float ic = rcp_fast(fmaxf(cnt, 1.f));
        float sigm = ss * ic;
        s_stat4[tid] = make_float4(sx * ic, sy * ic, sigm, __expf(10.f * sigm));
    }
    for (int j = tid; j < NID * KB * 2; j += 256) ((unsigned*)s_hist)[j] = 0u;
    for (int j = tid; j < 16 * 48; j += 256) ((float*)s_facc)[j] = 0.f;
    __syncthreads();

    float csx[NID], csy[NID], css[NID];
#pragma unroll
    for (int i = 0; i < NID; ++i) {
        float4 v = s_stat4[i];
        csx[i] = v.x; csy[i] = v.y; css[i] = v.w;
    }

    const int grp = tid >> 4;
    const int ib = b * HW;
    const float* sig   = pred + (((size_t)(b * 4 + 2)) << 18);
    const float* embx  = ws + WS_EMBX + ib;
    const float* emby  = ws + WS_EMBY + ib;
    const float* seedm = ws + WS_SEEDM + ib;

    auto doPx = [&](float exv, float eyv, float sdv, float gv, int iid) {
#pragma unroll
        for (int i = 0; i < NID; ++i) {
            float dx = exv - csx[i], dy = eyv - csy[i];
            float dist = __expf(-(dx * dx + dy * dy) * css[i]);
            float u1 = dist * (float)KB;
            bool m = (iid == i + 1);
            float bf = m ? ((float)KB - u1) : u1;
            int bk = min((int)bf, KB - 1);
            atomicAdd(&s_hist[i][bk * 2 + (m ? 0 : 1)], 1u);
        }
        if (iid > 0) {
            float4 st = s_stat4[iid - 1];            // runtime LDS index: fine
            float dx = exv - st.x, dy = eyv - st.y;
            float dist = __expf(-(dx * dx + dy * dy) * st.w);
            float dsg = gv - st.z;
            float e2 = sdv - dist;
            float* fa = &s_facc[grp][(iid - 1) * 3];
            atomicAdd(fa + 0, dsg * dsg);
            atomicAdd(fa + 1, e2 * e2);
            atomicAdd(fa + 2, dist);
        }
    };

#pragma unroll
    for (int u = 0; u < 2; ++u) {
        const int p = chunk * PXC + u * 1024 + tid * 4;
        const int4   i4 = *(const int4*)(inst + ib + p);
        const float4 exq = *(const float4*)(embx + p);
        const float4 eyq = *(const float4*)(emby + p);
        const float4 sdq = *(const float4*)(seedm + p);
        const float4 gq  = *(const float4*)(sig + p);
        doPx(exq.x, eyq.x, sdq.x, gq.x, i4.x);
        doPx(exq.y, eyq.y, sdq.y, gq.y, i4.y);
        doPx(exq.z, eyq.z, sdq.z, gq.z, i4.z);
        doPx(exq.w, eyq.w, sdq.w, gq.w, i4.w);
    }
    __syncthreads();

    // flush hist: plain coalesced stores (uint4), zero atomics
    unsigned* dst = (unsigned*)(ws + WS_HIST) + (size_t)(b * CHUNKS + chunk) * (NID * KB * 2);
    const uint4* src4 = (const uint4*)s_hist;
    uint4* dst4 = (uint4*)dst;
    for (int j = tid; j < NID * KB * 2 / 4; j += 256) dst4[j] = src4[j];

    // flush fg accums to replicas
    if (tid < 45) {
        float tot = 0.f;
#pragma unroll
        for (int q = 0; q < 16; ++q) tot += s_facc[q][tid];
        atomicAdd(ws + WS_ACCR + (chunk & 3) * 192 + b * 48 + tid, tot);
    }
}

// ---------------- kernel 3: Lovász hinge via bucket suffix-scan ----------------
// 60 blocks x 64 lanes; lane owns 4 consecutive buckets (2x uint4 per chunk copy).
__global__ __launch_bounds__(64) void lovaszKernel(float* __restrict__ ws) {
    const int t = blockIdx.x;           // b*15+i
    const int lane = threadIdx.x;
    const int b = t / NID, i = t % NID;
    float G = 0.f;
#pragma unroll
    for (int r = 0; r < 4; ++r) G += ws[WS_STATR + r * 256 + b * 60 + i * 4];

    float sum = 0.f;
    if (G > 0.f) {
        const unsigned* histU = (const unsigned*)(ws + WS_HIST);
        unsigned a0 = 0, a1 = 0, a2 = 0, a3 = 0, a4 = 0, a5 = 0, a6 = 0, a7 = 0;
        for (int c = 0; c < CHUNKS; ++c) {
            const unsigned* hb = histU + ((size_t)(b * CHUNKS + c) * NID + i) * (KB * 2) + lane * 8;
            uint4 q0 = *(const uint4*)(hb);
            uint4 q1 = *(const uint4*)(hb + 4);
            a0 += q0.x; a1 += q0.y; a2 += q0.z; a3 += q0.w;
            a4 += q1.x; a5 += q1.y; a6 += q1.z; a7 += q1.w;
        }
        // bucket k = lane*4+q : fg = a(2q), bg = a(2q+1)
        float fgs[4] = {(float)a0, (float)a2, (float)a4, (float)a6};
        float bgs[4] = {(float)a1, (float)a3, (float)a5, (float)a7};
        float Fl = fgs[0] + fgs[1] + fgs[2] + fgs[3];
        float Bl = bgs[0] + bgs[1] + bgs[2] + bgs[3];
        // inclusive suffix-scan across lanes (descending error = descending k)
        float Fs = Fl, Bs = Bl;
#pragma unroll
        for (int d = 1; d < 64; d <<= 1) {
            float fu = __shfl_down(Fs, d, 64);
            float bu = __shfl_down(Bs, d, 64);
            if (lane + d < 64) { Fs += fu; Bs += bu; }
        }
        float F = Fs - Fl, B = Bs - Bl;          // totals strictly above this lane's segment
        float Jprev = 1.f - (G - F) * rcp_fast(G + B);
        const float ew = 2.f / (float)KB;
#pragma unroll
        for (int q = 3; q >= 0; --q) {
            F += fgs[q]; B += bgs[q];
            float J = 1.f - (G - F) * rcp_fast(G + B);
            float ek = ((float)(lane * 4 + q) + 0.5f) * ew;
            sum += ek * (J - Jprev);
            Jprev = J;
        }
#pragma unroll
        for (int m = 32; m; m >>= 1) sum += __shfl_xor(sum, m, 64);
    }
    if (lane == 0) ws[WS_LOV + t] = sum;
}

// ---------------- kernel 4: compose final scalar ----------------
__global__ __launch_bounds__(64) void finalKernel(const float* __restrict__ ws,
                                                  float* __restrict__ out) {
    __shared__ float s_c[60][5];
    const int tid = threadIdx.x;
    if (tid < 60) {
        const int b = tid / NID, i = tid % NID;
        float cnt = 0.f, v = 0.f, sdl = 0.f, dm = 0.f;
#pragma unroll
        for (int r = 0; r < 4; ++r) {
            cnt += ws[WS_STATR + r * 256 + b * 60 + i * 4];
            const float* ac = ws + WS_ACCR + r * 192 + b * 48 + i * 3;
            v += ac[0]; sdl += ac[1]; dm += ac[2];
        }
        float pf = cnt > 0.f ? 1.f : 0.f;
        float ic = cnt > 0.f ? 1.f / cnt : 0.f;
        s_c[tid][0] = pf;
        s_c[tid][1] = pf * ws[WS_LOV + tid];
        s_c[tid][2] = pf * v * ic;
        s_c[tid][3] = pf * (1.f - dm * ic);
        s_c[tid][4] = pf * sdl;
    }
    __syncthreads();
    if (tid == 0) {
        float total = 0.f;
        for (int b = 0; b < NB; ++b) {
            float obj = 0.f, instl = 0.f, varl = 0.f, intral = 0.f, seedl = 0.f;
            for (int i = 0; i < NID; ++i) {
                const float* r = s_c[b * NID + i];
                obj += r[0]; instl += r[1]; varl += r[2]; intral += r[3]; seedl += r[4];
            }
            float objs = fmaxf(obj, 1.f);
            total += instl / objs
                   + 10.f * (varl / objs)
                   + (ws[WS_SEEDBG + b] + seedl) / (float)HW
                   + 5.f * intral;
        }
        out[0] = total * 0.25f;
    }
}

extern "C" void kernel_launch(void* const* d_in, const int* in_sizes, int n_in,
                              void* d_out, int out_size, void* d_ws, size_t ws_size,
                              hipStream_t stream) {
    const float* pred = (const float*)d_in[0];
    const int*   inst = (const int*)d_in[1];
    const int*   lab  = (const int*)d_in[2];
    float* ws  = (float*)d_ws;
    float* out = (float*)d_out;

    // control region only; hist copies and maps are fully overwritten
    hipMemsetAsync(d_ws, 0, WS_CTRL * sizeof(float), stream);
    prepKernel<<<dim3(256, NB), 256, 0, stream>>>(pred, inst, lab, ws);
    histKernel<<<dim3(CHUNKS, NB), 256, 0, stream>>>(pred, inst, ws);
    lovaszKernel<<<60, 64, 0, stream>>>(ws);
    finalKernel<<<1, 64, 0, stream>>>(ws, out);
}

// Round 5
// 79.681 us; speedup vs baseline: 2.6684x; 1.0869x over previous
//
#include <hip/hip_runtime.h>

// ---------------- problem constants ----------------
#define HW     262144      // 512*512
#define NB     4
#define NID    15
#define KB     256         // lovasz buckets; approx err <= (2/KB)*sum|dJ| ~ 0.008 << 1.045 thr
#define CHUNKS 128         // hist chunk-splits per image
#define PXC    (HW / CHUNKS)   // 2048 px per hist block

// ---------------- workspace layout (float offsets) ----------------
#define WS_STATR  0                         // [4 replicas][256] : (b*60 + i*4 + c)
#define WS_SEEDBG 1024                      // [4]
#define WS_ACCR   1028                      // [4 replicas][192] : (b*48 + i*3 + c)
#define WS_LOV    1796                      // [60]
#define WS_CTRL   2048                      // zeroed control region size
#define WS_HIST   2048                      // u32: [NB][CHUNKS][NID][KB], packed fg|bg<<16
#define HIST_U32  (NB * CHUNKS * NID * KB)  // 1,966,080
#define WS_EMBX   (WS_HIST + HIST_U32)
#define MAP_SZ    (NB * HW)
#define WS_EMBY   (WS_EMBX + MAP_SZ)
#define WS_SEEDM  (WS_EMBY + MAP_SZ)
#define WS_TOTAL  (WS_SEEDM + MAP_SZ)       // ~20.5 MB

__device__ __forceinline__ float rcp_fast(float x) { return __builtin_amdgcn_rcpf(x); }
__device__ __forceinline__ float fast_tanh(float x) {
    return 1.0f - 2.0f * rcp_fast(__expf(2.0f * x) + 1.0f);   // inf-safe
}
__device__ __forceinline__ float fast_sigmoid(float x) {
    return rcp_fast(1.0f + __expf(-x));
}

// ---------------- kernel 0: zero the control region (replaces hipMemsetAsync) --------
__global__ __launch_bounds__(256) void zeroKernel(float* __restrict__ ws) {
    ws[blockIdx.x * 256 + threadIdx.x] = 0.f;
}

// ---------------- kernel 1: stats + map precompute ----------------
// 256 blocks/image (1024 total). 4 px/thread. Stats into 16 per-lane-group
// LDS copies; flushed into 4 global replica arrays.
__global__ __launch_bounds__(256) void prepKernel(const float* __restrict__ pred,
                                                  const int* __restrict__ inst,
                                                  const int* __restrict__ lab,
                                                  float* __restrict__ ws) {
    __shared__ float s_acc[16][68];   // [group][(i*4+c) | 60=seed_bg]
    const int b   = blockIdx.y;
    const int tid = threadIdx.x;
    for (int j = tid; j < 16 * 68; j += 256) ((float*)s_acc)[j] = 0.f;
    __syncthreads();

    const int grp = tid >> 4;
    const int ib = b * HW;
    const float* p0 = pred + (((size_t)(b * 4 + 0)) << 18);
    const float* p1 = pred + (((size_t)(b * 4 + 1)) << 18);
    const float* p2 = pred + (((size_t)(b * 4 + 2)) << 18);
    const float* p3 = pred + (((size_t)(b * 4 + 3)) << 18);
    float* embx  = ws + WS_EMBX + ib;
    float* emby  = ws + WS_EMBY + ib;
    float* seedm = ws + WS_SEEDM + ib;
    const float inv511 = 1.0f / 511.0f;

    const int p = blockIdx.x * 1024 + tid * 4;
    const int4   i4 = *(const int4*)(inst + ib + p);
    const int4   l4 = *(const int4*)(lab + ib + p);
    const float4 a4 = *(const float4*)(p0 + p);
    const float4 b4 = *(const float4*)(p1 + p);
    const float4 g4 = *(const float4*)(p2 + p);
    const float4 t4 = *(const float4*)(p3 + p);
    const float xs0 = (float)(p & 511) * inv511;
    const float ys  = (float)(p >> 9) * inv511;

    float4 ex, ey, sd;
    ex.x = fast_tanh(a4.x) + xs0;
    ex.y = fast_tanh(a4.y) + xs0 + inv511;
    ex.z = fast_tanh(a4.z) + xs0 + 2.f * inv511;
    ex.w = fast_tanh(a4.w) + xs0 + 3.f * inv511;
    ey.x = fast_tanh(b4.x) + ys;
    ey.y = fast_tanh(b4.y) + ys;
    ey.z = fast_tanh(b4.z) + ys;
    ey.w = fast_tanh(b4.w) + ys;
    sd.x = fast_sigmoid(t4.x);
    sd.y = fast_sigmoid(t4.y);
    sd.z = fast_sigmoid(t4.z);
    sd.w = fast_sigmoid(t4.w);
    *(float4*)(embx + p)  = ex;
    *(float4*)(emby + p)  = ey;
    *(float4*)(seedm + p) = sd;

    float sbg = 0.f;
    sbg += (l4.x == 0) ? sd.x * sd.x : 0.f;
    sbg += (l4.y == 0) ? sd.y * sd.y : 0.f;
    sbg += (l4.z == 0) ? sd.z * sd.z : 0.f;
    sbg += (l4.w == 0) ? sd.w * sd.w : 0.f;

#define ACC_PX(IID, XS, SG)                                   \
    if ((IID) > 0) {                                          \
        float* a = &s_acc[grp][((IID) - 1) * 4];              \
        atomicAdd(a + 0, 1.f);                                \
        atomicAdd(a + 1, (XS));                               \
        atomicAdd(a + 2, ys);                                 \
        atomicAdd(a + 3, (SG));                               \
    }
    ACC_PX(i4.x, xs0, g4.x)
    ACC_PX(i4.y, xs0 + inv511, g4.y)
    ACC_PX(i4.z, xs0 + 2.f * inv511, g4.z)
    ACC_PX(i4.w, xs0 + 3.f * inv511, g4.w)
#undef ACC_PX

#pragma unroll
    for (int m = 32; m; m >>= 1) sbg += __shfl_xor(sbg, m, 64);
    if ((tid & 63) == 0) atomicAdd(&s_acc[grp][60], sbg);
    __syncthreads();

    if (tid < 61) {
        float tot = 0.f;
#pragma unroll
        for (int q = 0; q < 16; ++q) tot += s_acc[q][tid];
        if (tid < 60) atomicAdd(ws + WS_STATR + (blockIdx.x & 3) * 256 + b * 60 + tid, tot);
        else          atomicAdd(ws + WS_SEEDBG + b, tot);
    }
}

// ---------------- kernel 2: all-ids histogram + fg sums ----------------
// Grid (CHUNKS, NB) = 512 blocks (2/CU), 2048 px/block. Packed fg|bg<<16
// counts into 4 lane-group hist copies (+1-word pad to de-bank). Flush =
// sum of copies, plain coalesced stores (no global atomics).
#define HCOPY_STRIDE (NID * KB + 1)    // 3841 words: copies land on different banks
__global__ __launch_bounds__(256) void histKernel(const float* __restrict__ pred,
                                                  const int* __restrict__ inst,
                                                  float* __restrict__ ws) {
    __shared__ unsigned s_hist[4 * HCOPY_STRIDE];   // 61456 B
    __shared__ float4   s_stat4[NID];               // cx, cy, sigm, s
    __shared__ float    s_facc[8][48];              // fg accum copies

    const int b     = blockIdx.y;
    const int chunk = blockIdx.x;
    const int tid   = threadIdx.x;

    if (tid < NID) {
        float cnt = 0.f, sx = 0.f, sy = 0.f, ss = 0.f;
#pragma unroll
        for (int r = 0; r < 4; ++r) {
            const float* st = ws + WS_STATR + r * 256 + b * 60 + tid * 4;
            cnt += st[0]; sx += st[1]; sy += st[2]; ss += st[3];
        }
        float ic = rcp_fast(fmaxf(cnt, 1.f));
        float sigm = ss * ic;
        s_stat4[tid] = make_float4(sx * ic, sy * ic, sigm, __expf(10.f * sigm));
    }
    for (int j = tid; j < 4 * HCOPY_STRIDE; j += 256) s_hist[j] = 0u;
    for (int j = tid; j < 8 * 48; j += 256) ((float*)s_facc)[j] = 0.f;
    __syncthreads();

    float csx[NID], csy[NID], css[NID];
#pragma unroll
    for (int i = 0; i < NID; ++i) {
        float4 v = s_stat4[i];
        csx[i] = v.x; csy[i] = v.y; css[i] = v.w;
    }

    unsigned* myhist = &s_hist[((tid >> 4) & 3) * HCOPY_STRIDE];
    float* myfacc = s_facc[(tid >> 3) & 7];
    const int ib = b * HW;
    const float* sig   = pred + (((size_t)(b * 4 + 2)) << 18);
    const float* embx  = ws + WS_EMBX + ib;
    const float* emby  = ws + WS_EMBY + ib;
    const float* seedm = ws + WS_SEEDM + ib;

    auto doPx = [&](float exv, float eyv, float sdv, float gv, int iid) {
#pragma unroll
        for (int i = 0; i < NID; ++i) {
            float dx = exv - csx[i], dy = eyv - csy[i];
            float dist = __expf(-(dx * dx + dy * dy) * css[i]);
            float u1 = dist * (float)KB;
            bool m = (iid == i + 1);
            float bf = m ? ((float)KB - u1) : u1;
            int bk = min((int)bf, KB - 1);
            atomicAdd(&myhist[i * KB + bk], m ? 1u : 0x10000u);
        }
        if (iid > 0) {
            float4 st = s_stat4[iid - 1];
            float dx = exv - st.x, dy = eyv - st.y;
            float dist = __expf(-(dx * dx + dy * dy) * st.w);
            float dsg = gv - st.z;
            float e2 = sdv - dist;
            float* fa = &myfacc[(iid - 1) * 3];
            atomicAdd(fa + 0, dsg * dsg);
            atomicAdd(fa + 1, e2 * e2);
            atomicAdd(fa + 2, dist);
        }
    };

#pragma unroll
    for (int u = 0; u < 2; ++u) {
        const int p = chunk * PXC + u * 1024 + tid * 4;
        const int4   i4 = *(const int4*)(inst + ib + p);
        const float4 exq = *(const float4*)(embx + p);
        const float4 eyq = *(const float4*)(emby + p);
        const float4 sdq = *(const float4*)(seedm + p);
        const float4 gq  = *(const float4*)(sig + p);
        doPx(exq.x, eyq.x, sdq.x, gq.x, i4.x);
        doPx(exq.y, eyq.y, sdq.y, gq.y, i4.y);
        doPx(exq.z, eyq.z, sdq.z, gq.z, i4.z);
        doPx(exq.w, eyq.w, sdq.w, gq.w, i4.w);
    }
    __syncthreads();

    // flush: sum 4 copies, plain coalesced stores (fg,bg each <=2048 so no overflow)
    unsigned* dst = (unsigned*)(ws + WS_HIST) + (size_t)(b * CHUNKS + chunk) * (NID * KB);
    for (int j = tid; j < NID * KB; j += 256) {
        dst[j] = s_hist[j] + s_hist[HCOPY_STRIDE + j] +
                 s_hist[2 * HCOPY_STRIDE + j] + s_hist[3 * HCOPY_STRIDE + j];
    }

    if (tid < 45) {
        float tot = 0.f;
#pragma unroll
        for (int q = 0; q < 8; ++q) tot += s_facc[q][tid];
        atomicAdd(ws + WS_ACCR + (chunk & 3) * 192 + b * 48 + tid, tot);
    }
}

// ---------------- kernel 3: Lovász hinge via bucket suffix-scan ----------------
// 60 blocks x 256 threads. Wave wv sums chunks [32wv,32wv+32); LDS-combine;
// wave 0 does the 64-lane suffix scan over KB=256 buckets (4/lane).
__global__ __launch_bounds__(256) void lovaszKernel(float* __restrict__ ws) {
    __shared__ unsigned s_pf[4][KB];
    __shared__ unsigned s_pb[4][KB];
    const int t = blockIdx.x;           // b*15+i
    const int b = t / NID, i = t % NID;
    const int tid = threadIdx.x, wv = tid >> 6, lane = tid & 63;

    float G = 0.f;
#pragma unroll
    for (int r = 0; r < 4; ++r) G += ws[WS_STATR + r * 256 + b * 60 + i * 4];

    if (G > 0.f) {
        unsigned af0 = 0, af1 = 0, af2 = 0, af3 = 0;
        unsigned ab0 = 0, ab1 = 0, ab2 = 0, ab3 = 0;
        const unsigned* histU = (const unsigned*)(ws + WS_HIST);
        for (int k = 0; k < 32; ++k) {
            const int c = wv * 32 + k;
            const unsigned* hb = histU + ((size_t)(b * CHUNKS + c) * NID + i) * KB + lane * 4;
            uint4 q = *(const uint4*)hb;
            af0 += q.x & 0xffffu; ab0 += q.x >> 16;
            af1 += q.y & 0xffffu; ab1 += q.y >> 16;
            af2 += q.z & 0xffffu; ab2 += q.z >> 16;
            af3 += q.w & 0xffffu; ab3 += q.w >> 16;
        }
        s_pf[wv][lane * 4 + 0] = af0; s_pb[wv][lane * 4 + 0] = ab0;
        s_pf[wv][lane * 4 + 1] = af1; s_pb[wv][lane * 4 + 1] = ab1;
        s_pf[wv][lane * 4 + 2] = af2; s_pb[wv][lane * 4 + 2] = ab2;
        s_pf[wv][lane * 4 + 3] = af3; s_pb[wv][lane * 4 + 3] = ab3;
    }
    __syncthreads();

    float sum = 0.f;
    if (wv == 0 && G > 0.f) {
        float fgs[4], bgs[4];
#pragma unroll
        for (int q = 0; q < 4; ++q) {
            int k = lane * 4 + q;
            fgs[q] = (float)(s_pf[0][k] + s_pf[1][k] + s_pf[2][k] + s_pf[3][k]);
            bgs[q] = (float)(s_pb[0][k] + s_pb[1][k] + s_pb[2][k] + s_pb[3][k]);
        }
        float Fl = fgs[0] + fgs[1] + fgs[2] + fgs[3];
        float Bl = bgs[0] + bgs[1] + bgs[2] + bgs[3];
        // inclusive suffix-scan across lanes (descending error = descending k)
        float Fs = Fl, Bs = Bl;
#pragma unroll
        for (int d = 1; d < 64; d <<= 1) {
            float fu = __shfl_down(Fs, d, 64);
            float bu = __shfl_down(Bs, d, 64);
            if (lane + d < 64) { Fs += fu; Bs += bu; }
        }
        float F = Fs - Fl, B = Bs - Bl;        // totals strictly above this lane's segment
        float Jprev = 1.f - (G - F) * rcp_fast(G + B);
        const float ew = 2.f / (float)KB;
#pragma unroll
        for (int q = 3; q >= 0; --q) {
            F += fgs[q]; B += bgs[q];
            float J = 1.f - (G - F) * rcp_fast(G + B);
            float ek = ((float)(lane * 4 + q) + 0.5f) * ew;
            sum += ek * (J - Jprev);
            Jprev = J;
        }
#pragma unroll
        for (int m = 32; m; m >>= 1) sum += __shfl_xor(sum, m, 64);
    }
    if (tid == 0) ws[WS_LOV + t] = sum;
}

// ---------------- kernel 4: compose final scalar ----------------
__global__ __launch_bounds__(64) void finalKernel(const float* __restrict__ ws,
                                                  float* __restrict__ out) {
    __shared__ float s_c[60][5];
    const int tid = threadIdx.x;
    if (tid < 60) {
        const int b = tid / NID, i = tid % NID;
        float cnt = 0.f, v = 0.f, sdl = 0.f, dm = 0.f;
#pragma unroll
        for (int r = 0; r < 4; ++r) {
            cnt += ws[WS_STATR + r * 256 + b * 60 + i * 4];
            const float* ac = ws + WS_ACCR + r * 192 + b * 48 + i * 3;
            v += ac[0]; sdl += ac[1]; dm += ac[2];
        }
        float pf = cnt > 0.f ? 1.f : 0.f;
        float ic = cnt > 0.f ? 1.f / cnt : 0.f;
        s_c[tid][0] = pf;
        s_c[tid][1] = pf * ws[WS_LOV + tid];
        s_c[tid][2] = pf * v * ic;
        s_c[tid][3] = pf * (1.f - dm * ic);
        s_c[tid][4] = pf * sdl;
    }
    __syncthreads();
    if (tid == 0) {
        float total = 0.f;
        for (int b = 0; b < NB; ++b) {
            float obj = 0.f, instl = 0.f, varl = 0.f, intral = 0.f, seedl = 0.f;
            for (int i = 0; i < NID; ++i) {
                const float* r = s_c[b * NID + i];
                obj += r[0]; instl += r[1]; varl += r[2]; intral += r[3]; seedl += r[4];
            }
            float objs = fmaxf(obj, 1.f);
            total += instl / objs
                   + 10.f * (varl / objs)
                   + (ws[WS_SEEDBG + b] + seedl) / (float)HW
                   + 5.f * intral;
        }
        out[0] = total * 0.25f;
    }
}

extern "C" void kernel_launch(void* const* d_in, const int* in_sizes, int n_in,
                              void* d_out, int out_size, void* d_ws, size_t ws_size,
                              hipStream_t stream) {
    const float* pred = (const float*)d_in[0];
    const int*   inst = (const int*)d_in[1];
    const int*   lab  = (const int*)d_in[2];
    float* ws  = (float*)d_ws;
    float* out = (float*)d_out;

    zeroKernel<<<WS_CTRL / 256, 256, 0, stream>>>(ws);
    prepKernel<<<dim3(256, NB), 256, 0, stream>>>(pred, inst, lab, ws);
    histKernel<<<dim3(CHUNKS, NB), 256, 0, stream>>>(pred, inst, ws);
    lovaszKernel<<<60, 256, 0, stream>>>(ws);
    finalKernel<<<1, 64, 0, stream>>>(ws, out);
}